// Round 2
// baseline (642.241 us; speedup 1.0000x reference)
//
#include <hip/hip_runtime.h>
#include <math.h>

#define F 128
#define OUTDIM 64
#define NEG 0.2f
#define BN 128
#define KT 64

// ---------------- utility ----------------
__global__ void zero_ints(int* __restrict__ p, int n) {
    int i = blockIdx.x * blockDim.x + threadIdx.x;
    if (i < n) p[i] = 0;
}

// ---------------- CSR build ----------------
__global__ void hist_kernel(const int* __restrict__ src, const int* __restrict__ dst,
                            int* __restrict__ degF, int* __restrict__ degR, int E) {
    int e = blockIdx.x * blockDim.x + threadIdx.x;
    if (e < E) {
        atomicAdd(&degF[dst[e]], 1);
        atomicAdd(&degR[src[e]], 1);
    }
}

// inclusive scan, 1024 items/block, writes rs[i+1]; block totals to bsums
__global__ void scan_pass1(const int* __restrict__ degF, const int* __restrict__ degR,
                           int* __restrict__ rsF, int* __restrict__ rsR,
                           int* __restrict__ bsums, int N) {
    const int arr = blockIdx.y;
    const int* deg = arr ? degR : degF;
    int* rs = arr ? rsR : rsF;
    int tid = threadIdx.x;
    int base = blockIdx.x * 1024 + tid * 4;
    int v[4];
#pragma unroll
    for (int i = 0; i < 4; i++) v[i] = (base + i < N) ? deg[base + i] : 0;
    int s1 = v[0] + v[1] + v[2] + v[3];
    __shared__ int sd[256];
    sd[tid] = s1;
    __syncthreads();
    for (int off = 1; off < 256; off <<= 1) {
        int t = (tid >= off) ? sd[tid - off] : 0;
        __syncthreads();
        sd[tid] += t;
        __syncthreads();
    }
    int run = sd[tid] - s1;
#pragma unroll
    for (int i = 0; i < 4; i++) {
        run += v[i];
        if (base + i < N) rs[base + i + 1] = run;
    }
    if (tid == 255) bsums[arr * 128 + blockIdx.x] = sd[255];
    if (tid == 0 && blockIdx.x == 0) rs[0] = 0;
}

__global__ void scan_pass2(int* __restrict__ bsums, int nb) {
    int arr = blockIdx.y;
    int tid = threadIdx.x;  // 128
    __shared__ int sd[128];
    int v = (tid < nb) ? bsums[arr * 128 + tid] : 0;
    sd[tid] = v;
    __syncthreads();
    for (int off = 1; off < 128; off <<= 1) {
        int t = (tid >= off) ? sd[tid - off] : 0;
        __syncthreads();
        sd[tid] += t;
        __syncthreads();
    }
    bsums[arr * 128 + tid] = sd[tid];  // inclusive
}

__global__ void scan_pass3(int* __restrict__ rsF, int* __restrict__ rsR,
                           const int* __restrict__ bsums, int N) {
    int arr = blockIdx.y;
    if (blockIdx.x == 0) return;
    int* rs = arr ? rsR : rsF;
    int off = bsums[arr * 128 + blockIdx.x - 1];
    int base = blockIdx.x * 1024 + threadIdx.x * 4;
#pragma unroll
    for (int i = 0; i < 4; i++)
        if (base + i < N) rs[base + i + 1] += off;
}

__global__ void scatter_kernel(const int* __restrict__ src, const int* __restrict__ dst,
                               const int* __restrict__ rsF, const int* __restrict__ rsR,
                               int* __restrict__ curF, int* __restrict__ curR,
                               int* __restrict__ colF, int* __restrict__ colR, int E) {
    int e = blockIdx.x * blockDim.x + threadIdx.x;
    if (e < E) {
        int s = src[e], d = dst[e];
        int pf = rsF[d] + atomicAdd(&curF[d], 1);
        colF[pf] = s;
        int pr = rsR[s] + atomicAdd(&curR[s], 1);
        colR[pr] = d;
    }
}

// ---------------- per-node attention scalars from feature (both directions) ----------------
__global__ void sd4_kernel(const float* __restrict__ x,
                           const float* __restrict__ af_s, const float* __restrict__ af_d,
                           const float* __restrict__ ar_s, const float* __restrict__ ar_d,
                           float* __restrict__ sf, float* __restrict__ df,
                           float* __restrict__ sr, float* __restrict__ dr, int N) {
    int node = blockIdx.x * 4 + (threadIdx.x >> 6);
    int lane = threadIdx.x & 63;
    if (node >= N) return;
    const float2 xv = *(const float2*)&x[(size_t)node * F + 2 * lane];
    float2 a;
    a = *(const float2*)&af_s[2 * lane]; float vsf = xv.x * a.x + xv.y * a.y;
    a = *(const float2*)&af_d[2 * lane]; float vdf = xv.x * a.x + xv.y * a.y;
    a = *(const float2*)&ar_s[2 * lane]; float vsr = xv.x * a.x + xv.y * a.y;
    a = *(const float2*)&ar_d[2 * lane]; float vdr = xv.x * a.x + xv.y * a.y;
#pragma unroll
    for (int off = 32; off > 0; off >>= 1) {
        vsf += __shfl_xor(vsf, off);
        vdf += __shfl_xor(vdf, off);
        vsr += __shfl_xor(vsr, off);
        vdr += __shfl_xor(vdr, off);
    }
    if (lane == 0) { sf[node] = vsf; df[node] = vdf; sr[node] = vsr; dr[node] = vdr; }
}

// ---------------- one hop of attention aggregation (wave per dst node) ----------------
// online softmax over CSR segment; optional fused s/d dot for next hop
__global__ void agg_kernel(const float* __restrict__ hin, int ldin,
                           const float* __restrict__ s, const float* __restrict__ d,
                           const int* __restrict__ rs, const int* __restrict__ col,
                           float* __restrict__ hout, int ldout,
                           const float* __restrict__ a_s, const float* __restrict__ a_d,
                           float* __restrict__ s_out, float* __restrict__ d_out, int N) {
    int node = blockIdx.x * 4 + (threadIdx.x >> 6);
    int lane = threadIdx.x & 63;
    if (node >= N) return;
    float di = d[node];
    int beg = rs[node], end = rs[node + 1];
    float m = -INFINITY, l = 0.f;
    float ax = 0.f, ay = 0.f;
    for (int j = beg; j < end; ++j) {
        int sj = col[j];
        float e = s[sj] + di;
        e = e >= 0.f ? e : NEG * e;
        float nm = fmaxf(m, e);
        float sc = __expf(m - nm);
        float p = __expf(e - nm);
        l = l * sc + p;
        const float2 hv = *(const float2*)&hin[(size_t)sj * ldin + 2 * lane];
        ax = ax * sc + p * hv.x;
        ay = ay * sc + p * hv.y;
        m = nm;
    }
    float2 o;
    if (end > beg) {
        float inv = 1.f / (l + 1e-16f);
        o.x = ax * inv; o.y = ay * inv;
    } else {
        o.x = 0.f; o.y = 0.f;
    }
    *(float2*)&hout[(size_t)node * ldout + 2 * lane] = o;
    if (a_s) {  // fused next-hop s,d
        float2 a;
        a = *(const float2*)&a_s[2 * lane]; float vs = o.x * a.x + o.y * a.y;
        a = *(const float2*)&a_d[2 * lane]; float vd = o.x * a.x + o.y * a.y;
#pragma unroll
        for (int off = 32; off > 0; off >>= 1) {
            vs += __shfl_xor(vs, off);
            vd += __shfl_xor(vd, off);
        }
        if (lane == 0) { s_out[node] = vs; d_out[node] = vd; }
    }
}

// ---------------- fold W blocks: Weff[640][64] ----------------
// concat order: [x, h1f, h2f, x, h1r, h2r]; fold both x blocks together.
__global__ void weff_kernel(const float* __restrict__ W, float* __restrict__ Weff) {
    int i = blockIdx.x * blockDim.x + threadIdx.x;
    if (i >= 640 * 64) return;
    int r = i >> 6, o = i & 63;
    float v;
    if (r < 128)      v = W[r * 64 + o] + W[(r + 384) * 64 + o];   // x + x
    else if (r < 384) v = W[r * 64 + o];                            // h1f, h2f
    else              v = W[(r + 128) * 64 + o];                    // h1r, h2r
    Weff[i] = v;
}

// ---------------- final dense: out[N][64] = [x|hcat] @ Weff + b ----------------
__global__ __launch_bounds__(256) void gemm_kernel(
    const float* __restrict__ X0,    // feature [N][128]
    const float* __restrict__ H,     // hcat [N][512]
    const float* __restrict__ Weff,  // [640][64]
    const float* __restrict__ bias,  // [64]
    float* __restrict__ out, int N) {
    __shared__ float Xs[KT][BN + 4];  // transposed, pad 4 keeps 16B align + no conflicts
    __shared__ float Ws[KT][64];
    int tid = threadIdx.x;
    int tx = tid & 15, ty = tid >> 4;
    int nodeBase = blockIdx.x * BN;
    float acc[8][4];
#pragma unroll
    for (int i = 0; i < 8; i++)
#pragma unroll
        for (int j = 0; j < 4; j++) acc[i][j] = 0.f;

    for (int t = 0; t < 10; ++t) {
        const float* src; int ld, cb;
        if (t < 2) { src = X0; ld = 128; cb = t * 64; }
        else       { src = H;  ld = 512; cb = (t - 2) * 64; }
        // stage X tile: 128 rows x 64 k, 4 threads/row (64B contiguous per row-chunk)
        {
            int r0 = tid >> 2;            // 0..63
            int kc = (tid & 3) * 16;      // 0,16,32,48
#pragma unroll
            for (int h = 0; h < 2; h++) {
                int row = r0 + h * 64;
                int n = nodeBase + row;
                if (n < N) {
                    const float* p = src + (size_t)n * ld + cb + kc;
#pragma unroll
                    for (int q = 0; q < 4; q++) {
                        float4 v = *(const float4*)(p + q * 4);
                        Xs[kc + q * 4 + 0][row] = v.x;
                        Xs[kc + q * 4 + 1][row] = v.y;
                        Xs[kc + q * 4 + 2][row] = v.z;
                        Xs[kc + q * 4 + 3][row] = v.w;
                    }
                } else {
#pragma unroll
                    for (int q = 0; q < 4; q++) {
                        Xs[kc + q * 4 + 0][row] = 0.f;
                        Xs[kc + q * 4 + 1][row] = 0.f;
                        Xs[kc + q * 4 + 2][row] = 0.f;
                        Xs[kc + q * 4 + 3][row] = 0.f;
                    }
                }
            }
            // stage W tile: 64 rows x 64 cols
            int wr = tid >> 2, wc = (tid & 3) * 16;
            const float* wp = Weff + (size_t)(t * 64 + wr) * 64 + wc;
#pragma unroll
            for (int q = 0; q < 4; q++) {
                *(float4*)&Ws[wr][wc + q * 4] = *(const float4*)(wp + q * 4);
            }
        }
        __syncthreads();
#pragma unroll 4
        for (int k = 0; k < KT; k++) {
            float4 x0 = *(const float4*)&Xs[k][ty * 8];
            float4 x1 = *(const float4*)&Xs[k][ty * 8 + 4];
            float4 w4 = *(const float4*)&Ws[k][tx * 4];
            float xv[8] = {x0.x, x0.y, x0.z, x0.w, x1.x, x1.y, x1.z, x1.w};
            float wv[4] = {w4.x, w4.y, w4.z, w4.w};
#pragma unroll
            for (int i = 0; i < 8; i++)
#pragma unroll
                for (int j = 0; j < 4; j++) acc[i][j] += xv[i] * wv[j];
        }
        __syncthreads();
    }
    float4 bv = *(const float4*)&bias[tx * 4];
#pragma unroll
    for (int i = 0; i < 8; i++) {
        int n = nodeBase + ty * 8 + i;
        if (n < N) {
            float4 o;
            o.x = acc[i][0] + bv.x; o.y = acc[i][1] + bv.y;
            o.z = acc[i][2] + bv.z; o.w = acc[i][3] + bv.w;
            *(float4*)&out[(size_t)n * 64 + tx * 4] = o;
        }
    }
}

extern "C" void kernel_launch(void* const* d_in, const int* in_sizes, int n_in,
                              void* d_out, int out_size, void* d_ws, size_t ws_size,
                              hipStream_t stream) {
    const float* feature = (const float*)d_in[0];
    const int*   eidx    = (const int*)d_in[1];
    const float* af_s    = (const float*)d_in[2];
    const float* af_d    = (const float*)d_in[3];
    const float* ar_s    = (const float*)d_in[4];
    const float* ar_d    = (const float*)d_in[5];
    const float* W       = (const float*)d_in[6];
    const float* bias    = (const float*)d_in[7];
    float* out = (float*)d_out;
    const int N = in_sizes[0] / F;
    const int E = in_sizes[1] / 2;
    const int* src = eidx;       // edge_index[0]
    const int* dst = eidx + E;   // edge_index[1]

    char* ws = (char*)d_ws;
    size_t off = 0;
    auto alloc = [&](size_t b) { size_t r = off; off = (off + b + 255) & ~(size_t)255; return r; };
    float* hcat  = (float*)(ws + alloc((size_t)N * 512 * 4));  // [h1f|h2f|h1r|h2r]
    int*   rsF   = (int*)(ws + alloc((size_t)(N + 1) * 4));
    int*   rsR   = (int*)(ws + alloc((size_t)(N + 1) * 4));
    int*   colF  = (int*)(ws + alloc((size_t)E * 4));
    int*   colR  = (int*)(ws + alloc((size_t)E * 4));
    int*   ints4 = (int*)(ws + alloc((size_t)4 * N * 4));
    int *degF = ints4, *degR = ints4 + N, *curF = ints4 + 2 * N, *curR = ints4 + 3 * N;
    float* fls8 = (float*)(ws + alloc((size_t)8 * N * 4));
    float *sf = fls8, *df = fls8 + N, *sr = fls8 + 2 * (size_t)N, *dr = fls8 + 3 * (size_t)N;
    float *s2f = fls8 + 4 * (size_t)N, *d2f = fls8 + 5 * (size_t)N;
    float *s2r = fls8 + 6 * (size_t)N, *d2r = fls8 + 7 * (size_t)N;
    int*   bsums = (int*)(ws + alloc(256 * 4));
    float* Weff  = (float*)(ws + alloc(640 * 64 * 4));

    float* h1f = hcat + 0;
    float* h2f = hcat + 128;
    float* h1r = hcat + 256;
    float* h2r = hcat + 384;

    const int nb = (N + 1023) / 1024;
    zero_ints<<<(4 * N + 255) / 256, 256, 0, stream>>>(ints4, 4 * N);
    hist_kernel<<<(E + 255) / 256, 256, 0, stream>>>(src, dst, degF, degR, E);
    scan_pass1<<<dim3(nb, 2), 256, 0, stream>>>(degF, degR, rsF, rsR, bsums, N);
    scan_pass2<<<dim3(1, 2), 128, 0, stream>>>(bsums, nb);
    scan_pass3<<<dim3(nb, 2), 256, 0, stream>>>(rsF, rsR, bsums, N);
    scatter_kernel<<<(E + 255) / 256, 256, 0, stream>>>(src, dst, rsF, rsR, curF, curR, colF, colR, E);
    sd4_kernel<<<(N + 3) / 4, 256, 0, stream>>>(feature, af_s, af_d, ar_s, ar_d, sf, df, sr, dr, N);
    // hop 1 (fused next-hop s/d)
    agg_kernel<<<(N + 3) / 4, 256, 0, stream>>>(feature, F, sf, df, rsF, colF, h1f, 512,
                                                af_s, af_d, s2f, d2f, N);
    agg_kernel<<<(N + 3) / 4, 256, 0, stream>>>(feature, F, sr, dr, rsR, colR, h1r, 512,
                                                ar_s, ar_d, s2r, d2r, N);
    // hop 2
    agg_kernel<<<(N + 3) / 4, 256, 0, stream>>>(h1f, 512, s2f, d2f, rsF, colF, h2f, 512,
                                                (const float*)nullptr, (const float*)nullptr,
                                                (float*)nullptr, (float*)nullptr, N);
    agg_kernel<<<(N + 3) / 4, 256, 0, stream>>>(h1r, 512, s2r, d2r, rsR, colR, h2r, 512,
                                                (const float*)nullptr, (const float*)nullptr,
                                                (float*)nullptr, (float*)nullptr, N);
    weff_kernel<<<(640 * 64 + 255) / 256, 256, 0, stream>>>(W, Weff);
    gemm_kernel<<<(N + BN - 1) / BN, 256, 0, stream>>>(feature, hcat, Weff, bias, out, N);
}

// Round 3
// 555.238 us; speedup vs baseline: 1.1567x; 1.1567x over previous
//
#include <hip/hip_runtime.h>
#include <math.h>

#define F 128
#define OUTDIM 64
#define NEG 0.2f
#define BN 128
#define KT2 32

// ---------------- utility ----------------
__global__ void zero_ints(int* __restrict__ p, int n) {
    int i = blockIdx.x * blockDim.x + threadIdx.x;
    if (i < n) p[i] = 0;
}

// ---------------- CSR build ----------------
__global__ void hist_kernel(const int* __restrict__ src, const int* __restrict__ dst,
                            int* __restrict__ degF, int* __restrict__ degR, int E) {
    int e = blockIdx.x * blockDim.x + threadIdx.x;
    if (e < E) {
        atomicAdd(&degF[dst[e]], 1);
        atomicAdd(&degR[src[e]], 1);
    }
}

__global__ void scan_pass1(const int* __restrict__ degF, const int* __restrict__ degR,
                           int* __restrict__ rsF, int* __restrict__ rsR,
                           int* __restrict__ bsums, int N) {
    const int arr = blockIdx.y;
    const int* deg = arr ? degR : degF;
    int* rs = arr ? rsR : rsF;
    int tid = threadIdx.x;
    int base = blockIdx.x * 1024 + tid * 4;
    int v[4];
#pragma unroll
    for (int i = 0; i < 4; i++) v[i] = (base + i < N) ? deg[base + i] : 0;
    int s1 = v[0] + v[1] + v[2] + v[3];
    __shared__ int sd[256];
    sd[tid] = s1;
    __syncthreads();
    for (int off = 1; off < 256; off <<= 1) {
        int t = (tid >= off) ? sd[tid - off] : 0;
        __syncthreads();
        sd[tid] += t;
        __syncthreads();
    }
    int run = sd[tid] - s1;
#pragma unroll
    for (int i = 0; i < 4; i++) {
        run += v[i];
        if (base + i < N) rs[base + i + 1] = run;
    }
    if (tid == 255) bsums[arr * 128 + blockIdx.x] = sd[255];
    if (tid == 0 && blockIdx.x == 0) rs[0] = 0;
}

__global__ void scan_pass2(int* __restrict__ bsums, int nb) {
    int arr = blockIdx.y;
    int tid = threadIdx.x;  // 128
    __shared__ int sd[128];
    int v = (tid < nb) ? bsums[arr * 128 + tid] : 0;
    sd[tid] = v;
    __syncthreads();
    for (int off = 1; off < 128; off <<= 1) {
        int t = (tid >= off) ? sd[tid - off] : 0;
        __syncthreads();
        sd[tid] += t;
        __syncthreads();
    }
    bsums[arr * 128 + tid] = sd[tid];
}

__global__ void scan_pass3(int* __restrict__ rsF, int* __restrict__ rsR,
                           const int* __restrict__ bsums, int N) {
    int arr = blockIdx.y;
    if (blockIdx.x == 0) return;
    int* rs = arr ? rsR : rsF;
    int off = bsums[arr * 128 + blockIdx.x - 1];
    int base = blockIdx.x * 1024 + threadIdx.x * 4;
#pragma unroll
    for (int i = 0; i < 4; i++)
        if (base + i < N) rs[base + i + 1] += off;
}

__global__ void scatter_kernel(const int* __restrict__ src, const int* __restrict__ dst,
                               const int* __restrict__ rsF, const int* __restrict__ rsR,
                               int* __restrict__ curF, int* __restrict__ curR,
                               int* __restrict__ colF, int* __restrict__ colR, int E) {
    int e = blockIdx.x * blockDim.x + threadIdx.x;
    if (e < E) {
        int s = src[e], d = dst[e];
        int pf = rsF[d] + atomicAdd(&curF[d], 1);
        colF[pf] = s;
        int pr = rsR[s] + atomicAdd(&curR[s], 1);
        colR[pr] = d;
    }
}

// ---------------- per-node attention scalars ----------------
__global__ void sd4_kernel(const float* __restrict__ x,
                           const float* __restrict__ af_s, const float* __restrict__ af_d,
                           const float* __restrict__ ar_s, const float* __restrict__ ar_d,
                           float* __restrict__ sf, float* __restrict__ df,
                           float* __restrict__ sr, float* __restrict__ dr, int N) {
    int node = blockIdx.x * 4 + (threadIdx.x >> 6);
    int lane = threadIdx.x & 63;
    if (node >= N) return;
    const float2 xv = *(const float2*)&x[(size_t)node * F + 2 * lane];
    float2 a;
    a = *(const float2*)&af_s[2 * lane]; float vsf = xv.x * a.x + xv.y * a.y;
    a = *(const float2*)&af_d[2 * lane]; float vdf = xv.x * a.x + xv.y * a.y;
    a = *(const float2*)&ar_s[2 * lane]; float vsr = xv.x * a.x + xv.y * a.y;
    a = *(const float2*)&ar_d[2 * lane]; float vdr = xv.x * a.x + xv.y * a.y;
#pragma unroll
    for (int off = 32; off > 0; off >>= 1) {
        vsf += __shfl_xor(vsf, off);
        vdf += __shfl_xor(vdf, off);
        vsr += __shfl_xor(vsr, off);
        vdr += __shfl_xor(vdr, off);
    }
    if (lane == 0) { sf[node] = vsf; df[node] = vdf; sr[node] = vsr; dr[node] = vdr; }
}

// ---------------- one hop of attention aggregation ----------------
// Phase 1: lane-parallel scalar softmax over the segment (1 edge/lane).
// Phase 2: 4-deep pipelined weighted row gather (shuffle-broadcast src & p).
__global__ void agg_kernel(const float* __restrict__ hin, int ldin,
                           const float* __restrict__ s, const float* __restrict__ d,
                           const int* __restrict__ rs, const int* __restrict__ col,
                           float* __restrict__ hout, int ldout,
                           const float* __restrict__ a_s, const float* __restrict__ a_d,
                           float* __restrict__ s_out, float* __restrict__ d_out, int N) {
    int node = blockIdx.x * 4 + (threadIdx.x >> 6);
    int lane = threadIdx.x & 63;
    if (node >= N) return;
    float di = d[node];
    int beg = rs[node], end = rs[node + 1];
    int deg = end - beg;
    float m = -INFINITY, l = 0.f;
    float ax = 0.f, ay = 0.f;

    for (int base = 0; base < deg; base += 64) {
        int cnt = min(64, deg - base);
        int sj_l = 0;
        float e_l = -INFINITY;
        if (lane < cnt) {
            sj_l = col[beg + base + lane];
            float e = s[sj_l] + di;
            e_l = (e >= 0.f) ? e : NEG * e;
        }
        // wave max of e
        float bm = e_l;
#pragma unroll
        for (int off = 32; off > 0; off >>= 1) bm = fmaxf(bm, __shfl_xor(bm, off));
        float nm = fmaxf(m, bm);
        float p_l = (lane < cnt) ? __expf(e_l - nm) : 0.f;
        float ps = p_l;
#pragma unroll
        for (int off = 32; off > 0; off >>= 1) ps += __shfl_xor(ps, off);
        float sc = (m == -INFINITY) ? 0.f : __expf(m - nm);
        l = l * sc + ps;
        ax *= sc; ay *= sc;
        // pipelined accumulation, 4 rows in flight
        for (int j0 = 0; j0 < cnt; j0 += 4) {
            int rem = cnt - j0;
            float2 hv0, hv1, hv2, hv3;
            float p0 = 0.f, p1 = 0.f, p2 = 0.f, p3 = 0.f;
            {
                int sj = __shfl(sj_l, j0);
                p0 = __shfl(p_l, j0);
                hv0 = *(const float2*)&hin[(size_t)sj * ldin + 2 * lane];
            }
            if (rem > 1) {
                int sj = __shfl(sj_l, j0 + 1);
                p1 = __shfl(p_l, j0 + 1);
                hv1 = *(const float2*)&hin[(size_t)sj * ldin + 2 * lane];
            } else { hv1.x = 0.f; hv1.y = 0.f; }
            if (rem > 2) {
                int sj = __shfl(sj_l, j0 + 2);
                p2 = __shfl(p_l, j0 + 2);
                hv2 = *(const float2*)&hin[(size_t)sj * ldin + 2 * lane];
            } else { hv2.x = 0.f; hv2.y = 0.f; }
            if (rem > 3) {
                int sj = __shfl(sj_l, j0 + 3);
                p3 = __shfl(p_l, j0 + 3);
                hv3 = *(const float2*)&hin[(size_t)sj * ldin + 2 * lane];
            } else { hv3.x = 0.f; hv3.y = 0.f; }
            ax += p0 * hv0.x + p1 * hv1.x + p2 * hv2.x + p3 * hv3.x;
            ay += p0 * hv0.y + p1 * hv1.y + p2 * hv2.y + p3 * hv3.y;
        }
        m = nm;
    }

    float2 o;
    if (deg > 0) {
        float inv = 1.f / (l + 1e-16f);
        o.x = ax * inv; o.y = ay * inv;
    } else {
        o.x = 0.f; o.y = 0.f;
    }
    *(float2*)&hout[(size_t)node * ldout + 2 * lane] = o;
    if (a_s) {
        float2 a;
        a = *(const float2*)&a_s[2 * lane]; float vs = o.x * a.x + o.y * a.y;
        a = *(const float2*)&a_d[2 * lane]; float vd = o.x * a.x + o.y * a.y;
#pragma unroll
        for (int off = 32; off > 0; off >>= 1) {
            vs += __shfl_xor(vs, off);
            vd += __shfl_xor(vd, off);
        }
        if (lane == 0) { s_out[node] = vs; d_out[node] = vd; }
    }
}

// ---------------- fold W blocks: Weff[640][64] ----------------
__global__ void weff_kernel(const float* __restrict__ W, float* __restrict__ Weff) {
    int i = blockIdx.x * blockDim.x + threadIdx.x;
    if (i >= 640 * 64) return;
    int r = i >> 6, o = i & 63;
    float v;
    if (r < 128)      v = W[r * 64 + o] + W[(r + 384) * 64 + o];
    else if (r < 384) v = W[r * 64 + o];
    else              v = W[(r + 128) * 64 + o];
    Weff[i] = v;
}

// ---------------- final dense: out[N][64] = [x|hcat] @ Weff + b ----------------
// KT=32: LDS 25.6KB -> 6 blocks/CU. X tile transposed with row-XOR swizzle
// (row ^ ((k>>4)<<4)): the two 16-k halves hit disjoint bank halves -> 2-way
// (free) staging writes. Ws stride 68 (== 4 mod 32): 2-way writes, aligned b128.
__global__ __launch_bounds__(256) void gemm_kernel(
    const float* __restrict__ X0,    // [N][128]
    const float* __restrict__ H,     // [N][512]
    const float* __restrict__ Weff,  // [640][64]
    const float* __restrict__ bias,  // [64]
    float* __restrict__ out, int N) {
    __shared__ float Xs[KT2][BN + 4];  // 32 x 132
    __shared__ float Ws[KT2][68];
    int tid = threadIdx.x;
    int tx = tid & 15, ty = tid >> 4;
    int nodeBase = blockIdx.x * BN;
    int srow = tid >> 1;          // 0..127
    int half = tid & 1;           // k-half
    int rowx = srow ^ (half << 4);
    float acc[8][4];
#pragma unroll
    for (int i = 0; i < 8; i++)
#pragma unroll
        for (int j = 0; j < 4; j++) acc[i][j] = 0.f;

    for (int t = 0; t < 20; ++t) {
        const float* src; int ld, cb;
        if (t < 4) { src = X0; ld = 128; cb = t * 32; }
        else       { src = H;  ld = 512; cb = (t - 4) * 32; }
        // stage X: thread covers 64B of one row
        {
            int n = nodeBase + srow;
            int kb = half * 16;
            if (n < N) {
                const float* p = src + (size_t)n * ld + cb + kb;
#pragma unroll
                for (int q = 0; q < 4; q++) {
                    float4 v = *(const float4*)(p + q * 4);
                    Xs[kb + q * 4 + 0][rowx] = v.x;
                    Xs[kb + q * 4 + 1][rowx] = v.y;
                    Xs[kb + q * 4 + 2][rowx] = v.z;
                    Xs[kb + q * 4 + 3][rowx] = v.w;
                }
            } else {
#pragma unroll
                for (int q = 0; q < 4; q++) {
                    Xs[kb + q * 4 + 0][rowx] = 0.f;
                    Xs[kb + q * 4 + 1][rowx] = 0.f;
                    Xs[kb + q * 4 + 2][rowx] = 0.f;
                    Xs[kb + q * 4 + 3][rowx] = 0.f;
                }
            }
        }
        // stage W: 2 linear float4 per thread
#pragma unroll
        for (int q = 0; q < 2; q++) {
            int f = 2 * tid + q;               // 0..511
            int wr = f >> 4, wc4 = f & 15;
            *(float4*)&Ws[wr][wc4 * 4] =
                *(const float4*)&Weff[(size_t)(t * 32 + wr) * 64 + wc4 * 4];
        }
        __syncthreads();
#pragma unroll
        for (int k = 0; k < KT2; k++) {
            const int flip = (k >> 4) << 4;
            float4 x0 = *(const float4*)&Xs[k][(ty * 8) ^ flip];
            float4 x1 = *(const float4*)&Xs[k][(ty * 8 + 4) ^ flip];
            float4 w4 = *(const float4*)&Ws[k][tx * 4];
            float xv[8] = {x0.x, x0.y, x0.z, x0.w, x1.x, x1.y, x1.z, x1.w};
            float wv[4] = {w4.x, w4.y, w4.z, w4.w};
#pragma unroll
            for (int i = 0; i < 8; i++)
#pragma unroll
                for (int j = 0; j < 4; j++) acc[i][j] += xv[i] * wv[j];
        }
        __syncthreads();
    }
    float4 bv = *(const float4*)&bias[tx * 4];
#pragma unroll
    for (int i = 0; i < 8; i++) {
        int n = nodeBase + ty * 8 + i;
        if (n < N) {
            float4 o;
            o.x = acc[i][0] + bv.x; o.y = acc[i][1] + bv.y;
            o.z = acc[i][2] + bv.z; o.w = acc[i][3] + bv.w;
            *(float4*)&out[(size_t)n * 64 + tx * 4] = o;
        }
    }
}

extern "C" void kernel_launch(void* const* d_in, const int* in_sizes, int n_in,
                              void* d_out, int out_size, void* d_ws, size_t ws_size,
                              hipStream_t stream) {
    const float* feature = (const float*)d_in[0];
    const int*   eidx    = (const int*)d_in[1];
    const float* af_s    = (const float*)d_in[2];
    const float* af_d    = (const float*)d_in[3];
    const float* ar_s    = (const float*)d_in[4];
    const float* ar_d    = (const float*)d_in[5];
    const float* W       = (const float*)d_in[6];
    const float* bias    = (const float*)d_in[7];
    float* out = (float*)d_out;
    const int N = in_sizes[0] / F;
    const int E = in_sizes[1] / 2;
    const int* src = eidx;
    const int* dst = eidx + E;

    char* ws = (char*)d_ws;
    size_t off = 0;
    auto alloc = [&](size_t b) { size_t r = off; off = (off + b + 255) & ~(size_t)255; return r; };
    float* hcat  = (float*)(ws + alloc((size_t)N * 512 * 4));  // [h1f|h2f|h1r|h2r]
    int*   rsF   = (int*)(ws + alloc((size_t)(N + 1) * 4));
    int*   rsR   = (int*)(ws + alloc((size_t)(N + 1) * 4));
    int*   colF  = (int*)(ws + alloc((size_t)E * 4));
    int*   colR  = (int*)(ws + alloc((size_t)E * 4));
    int*   ints4 = (int*)(ws + alloc((size_t)4 * N * 4));
    int *degF = ints4, *degR = ints4 + N, *curF = ints4 + 2 * N, *curR = ints4 + 3 * N;
    float* fls8 = (float*)(ws + alloc((size_t)8 * N * 4));
    float *sf = fls8, *df = fls8 + N, *sr = fls8 + 2 * (size_t)N, *dr = fls8 + 3 * (size_t)N;
    float *s2f = fls8 + 4 * (size_t)N, *d2f = fls8 + 5 * (size_t)N;
    float *s2r = fls8 + 6 * (size_t)N, *d2r = fls8 + 7 * (size_t)N;
    int*   bsums = (int*)(ws + alloc(256 * 4));
    float* Weff  = (float*)(ws + alloc(640 * 64 * 4));

    float* h1f = hcat + 0;
    float* h2f = hcat + 128;
    float* h1r = hcat + 256;
    float* h2r = hcat + 384;

    const int nb = (N + 1023) / 1024;
    zero_ints<<<(4 * N + 255) / 256, 256, 0, stream>>>(ints4, 4 * N);
    hist_kernel<<<(E + 255) / 256, 256, 0, stream>>>(src, dst, degF, degR, E);
    scan_pass1<<<dim3(nb, 2), 256, 0, stream>>>(degF, degR, rsF, rsR, bsums, N);
    scan_pass2<<<dim3(1, 2), 128, 0, stream>>>(bsums, nb);
    scan_pass3<<<dim3(nb, 2), 256, 0, stream>>>(rsF, rsR, bsums, N);
    scatter_kernel<<<(E + 255) / 256, 256, 0, stream>>>(src, dst, rsF, rsR, curF, curR, colF, colR, E);
    sd4_kernel<<<(N + 3) / 4, 256, 0, stream>>>(feature, af_s, af_d, ar_s, ar_d, sf, df, sr, dr, N);
    agg_kernel<<<(N + 3) / 4, 256, 0, stream>>>(feature, F, sf, df, rsF, colF, h1f, 512,
                                                af_s, af_d, s2f, d2f, N);
    agg_kernel<<<(N + 3) / 4, 256, 0, stream>>>(feature, F, sr, dr, rsR, colR, h1r, 512,
                                                ar_s, ar_d, s2r, d2r, N);
    agg_kernel<<<(N + 3) / 4, 256, 0, stream>>>(h1f, 512, s2f, d2f, rsF, colF, h2f, 512,
                                                (const float*)nullptr, (const float*)nullptr,
                                                (float*)nullptr, (float*)nullptr, N);
    agg_kernel<<<(N + 3) / 4, 256, 0, stream>>>(h1r, 512, s2r, d2r, rsR, colR, h2r, 512,
                                                (const float*)nullptr, (const float*)nullptr,
                                                (float*)nullptr, (float*)nullptr, N);
    weff_kernel<<<(640 * 64 + 255) / 256, 256, 0, stream>>>(W, Weff);
    gemm_kernel<<<(N + BN - 1) / BN, 256, 0, stream>>>(feature, hcat, Weff, bias, out, N);
}